// Round 9
// baseline (163.556 us; speedup 1.0000x reference)
//
#include <hip/hip_runtime.h>
#include <hip/hip_bf16.h>

#define NROWS 8192
#define KDIM  256
#define NT    64                  // NROWS / 128
#define NBLK  (NT * (NT + 1) / 2) // 2080 upper-triangular 128x128 tiles

typedef __attribute__((ext_vector_type(4))) float f32x4;

// async global->LDS, 16B per lane; LDS dest is wave-uniform base + lane*16
#define GLD(gp, lp)                                                            \
  __builtin_amdgcn_global_load_lds(                                            \
      (const __attribute__((address_space(1))) void*)(gp),                     \
      (__attribute__((address_space(3))) void*)(lp), 16, 0, 0)

// ---------------------------------------------------------------------------
// Kernel 1: fp32 -> fp8 e4m3 convert + per-row sum of squares. One wave per
// row (64 lanes x float4 = 256), barrier-free. Row 0 zeroes accumulators.
// ---------------------------------------------------------------------------
__global__ void prep_kernel(const float* __restrict__ samples,
                            unsigned char* __restrict__ sf8,
                            float* __restrict__ sq,
                            float* __restrict__ accg) {
  int t = threadIdx.x, lane = t & 63, wv = t >> 6;
  int row = blockIdx.x * 4 + wv;                    // grid 2048 x 256
  float4 v = ((const float4*)samples)[(size_t)row * 64 + lane];
  int pk0 = __builtin_amdgcn_cvt_pk_fp8_f32(v.x, v.y, 0, false);
  int pk1 = __builtin_amdgcn_cvt_pk_fp8_f32(v.z, v.w, 0, false);
  ((unsigned int*)sf8)[(size_t)row * 64 + lane] =
      (unsigned)(pk0 & 0xffff) | ((unsigned)pk1 << 16);
  float p = v.x * v.x + v.y * v.y + v.z * v.z + v.w * v.w;
#pragma unroll
  for (int off = 32; off; off >>= 1) p += __shfl_down(p, off);
  if (lane == 0) sq[row] = p;
  if (row == 0 && lane < 2) accg[lane] = 0.0f;
}

// decode triangular block index b -> (bi, bj), bi <= bj  (verified absmax 0.0)
__device__ inline void decode_tile(int b, int& bi, int& bj) {
  float disc = (2.0f * NT + 1.0f) * (2.0f * NT + 1.0f) - 8.0f * (float)b;
  bi = (int)(((2.0f * NT + 1.0f) - sqrtf(disc)) * 0.5f);
  if (bi < 0) bi = 0;
  if (bi > NT - 1) bi = NT - 1;
  while (bi > 0 && (bi * NT - bi * (bi - 1) / 2) > b) --bi;
  while (((bi + 1) * NT - (bi + 1) * bi / 2) <= b) ++bi;
  bj = bi + (b - (bi * NT - bi * (bi - 1) / 2));
}

// ---------------------------------------------------------------------------
// Kernel 2: m97-shaped — ONE 128x128 tile per block, 2080 blocks, 256 threads
// = 4 waves, each wave 32 rows x 128 cols (2x8 grid of 16x16x32 fp8 MFMAs).
// A fragments in registers (no LDS, no barrier); B single-buffered in 32 KB
// LDS -> ~3 blocks/CU co-resident so the per-tile staging drain of one block
// overlaps other blocks' MFMA/VALU (m114 co-scheduling — the thing rounds
// 4-8's 1-block/CU persistent variants lost). Two barriers per block total.
// ---------------------------------------------------------------------------
__global__ __launch_bounds__(256) void pair_kernel(
    const unsigned char* __restrict__ sf8, const float* __restrict__ sq,
    const int* __restrict__ labels, float* __restrict__ accg) {

  __shared__ __align__(16) unsigned char Bs[32 * 1024];

  int t = threadIdx.x;
  int lane = t & 63;
  int w = t >> 6;                      // 0..3: row-band w*32..+32
  int lr4 = lane >> 4, pc = lane & 15; // staging: row-in-region, phys chunk
  int r = lane & 15;                   // fragment row/col within 16
  int ko = lane >> 4;                  // k-group: k-bytes ko*8
  int kq = ko >> 1, hf = (ko & 1) * 8;
  int q4 = ko * 4;

  int bi, bj;
  decode_tile((int)blockIdx.x, bi, bj);
  int rowA0 = bi * 128, rowB0 = bj * 128;

  // ---- stage B first (async GLDs fly while we load A + scalars) ----
  // wave w stages regions w*8..w*8+7 (4 rows = 1KB each); XOR-16B swizzle
  // applied on the GLOBAL side (LDS dest stays wave-uniform + lane*16)
#pragma unroll
  for (int p = 0; p < 8; ++p) {
    int region = w * 8 + p;
    int rr = region * 4 + lr4;
    int c = pc ^ (rr & 15);
    GLD(sf8 + (size_t)(rowB0 + rr) * KDIM + c * 16, &Bs[region * 1024]);
  }

  // ---- A fragments (32 rows x K=256 -> 32 VGPRs) + A-side scalars ----
  long af[2][8];
#pragma unroll
  for (int i = 0; i < 2; i++) {
    const unsigned char* Ar =
        sf8 + (size_t)(rowA0 + w * 32 + i * 16 + r) * KDIM + ko * 8;
#pragma unroll
    for (int kc = 0; kc < 8; kc++) af[i][kc] = *(const long*)(Ar + kc * 32);
  }
  float sqa[8];
  int laa[8];
#pragma unroll
  for (int i = 0; i < 2; i++)
#pragma unroll
    for (int q = 0; q < 4; q++) {
      int gr = rowA0 + w * 32 + i * 16 + q4 + q;
      sqa[i * 4 + q] = sq[gr];
      laa[i * 4 + q] = labels[gr];
    }
  // B-side scalars (cols)
  float sqb[8];
  int lab[8];
#pragma unroll
  for (int j = 0; j < 8; j++) {
    int gc = rowB0 + j * 16 + r;
    sqb[j] = sq[gc];
    lab[j] = labels[gc];
  }

  __syncthreads();  // drains staging GLDs; Bs ready

  // ---- MFMA phase: 128 MFMAs/wave, B frags from LDS, A from registers ----
  f32x4 acc[2][8];
#pragma unroll
  for (int i = 0; i < 2; i++)
#pragma unroll
    for (int j = 0; j < 8; j++) acc[i][j] = (f32x4){0.f, 0.f, 0.f, 0.f};

#pragma unroll
  for (int kc = 0; kc < 8; ++kc) {
    long bfr[8];
#pragma unroll
    for (int j = 0; j < 8; j++) {
      bfr[j] = *(const long*)(&Bs[(j * 16 + r) * 256 +
                                  (((kc * 2 + kq) ^ r) * 16) + hf]);
    }
#pragma unroll
    for (int i = 0; i < 2; i++)
#pragma unroll
      for (int j = 0; j < 8; j++)
        acc[i][j] = __builtin_amdgcn_mfma_f32_16x16x32_fp8_fp8(
            af[i][kc], bfr[j], acc[i][j], 0, 0, 0);
  }

  // ---- epilogue: gram -> S -> masked sums ----
  // C/D layout: col = lane&15 (n), row = (lane>>4)*4 + reg (m)
  float s1 = 0.f, s2 = 0.f;
#pragma unroll
  for (int j = 0; j < 8; j++) {
#pragma unroll
    for (int i = 0; i < 2; i++) {
#pragma unroll
      for (int q = 0; q < 4; q++) {
        float S = (sqa[i * 4 + q] + sqb[j] - 2.0f * acc[i][j][q]) *
                  (1.0f / 256.0f);
        if (laa[i * 4 + q] == lab[j]) s1 += S;
        else                          s2 += fmaxf(0.f, 1.f - S);
      }
    }
  }
#pragma unroll
  for (int off = 32; off; off >>= 1) {
    s1 += __shfl_down(s1, off);
    s2 += __shfl_down(s2, off);
  }
  __syncthreads();  // all waves done reading Bs; reuse as reduction scratch
  float* red = (float*)&Bs[0];
  if (lane == 0) { red[w] = s1; red[4 + w] = s2; }
  __syncthreads();
  if (t == 0) {
    float wt = (bi == bj) ? 1.0f : 2.0f;  // off-diagonal tiles count twice
    atomicAdd(&accg[0], (red[0] + red[1] + red[2] + red[3]) * wt);
    atomicAdd(&accg[1], (red[4] + red[5] + red[6] + red[7]) * wt);
  }
}

// ---------------------------------------------------------------------------
// Kernel 3: final scalar
// ---------------------------------------------------------------------------
__global__ void finalize_kernel(const float* __restrict__ accg,
                                float* __restrict__ out) {
  out[0] = 10.0f * (accg[0] + accg[1]) *
           (1.0f / ((float)NROWS * (float)NROWS));
}

extern "C" void kernel_launch(void* const* d_in, const int* in_sizes, int n_in,
                              void* d_out, int out_size, void* d_ws,
                              size_t ws_size, hipStream_t stream) {
  // inputs: 0=merged (unused), 1=input1 (unused), 2=samples, 3=labels
  const float* samples = (const float*)d_in[2];
  const int*   labels  = (const int*)d_in[3];

  char* ws = (char*)d_ws;
  unsigned char* sf8 = (unsigned char*)ws;                        // 2 MiB fp8
  float* sq   = (float*)(ws + (size_t)NROWS * KDIM);              // 32 KiB
  float* accg = (float*)(ws + (size_t)NROWS * KDIM + NROWS * 4);  // 8 B
  float* out  = (float*)d_out;

  prep_kernel<<<NROWS / 4, 256, 0, stream>>>(samples, sf8, sq, accg);
  pair_kernel<<<NBLK, 256, 0, stream>>>(sf8, sq, labels, accg);
  finalize_kernel<<<1, 1, 0, stream>>>(accg, out);
}